// Round 1
// baseline (760.009 us; speedup 1.0000x reference)
//
#include <hip/hip_runtime.h>

#define HW   36864      // 192*192
#define NPOS 73728      // B*HW, B=2
#define EPSV 1e-5f

// channel-slot layout in workspace (each slot = NPOS floats)
#define S1_HF1  0
#define S1_FD1  20
#define S1_PHU1 50
#define S1_PHL1 70
#define S1_HD1  90
#define S2_HF2  160
#define S2_FD2  170
#define S2_PHU2 200
#define S2_PHL2 210
#define S2_HD2  220
#define S3_FU   0       // reuse stage-1 slots (dead by stage 3)
#define S3_HU   20
#define S3_PU   50
#define ST3_FU  290     // stat-channel bases for stage 3
#define ST3_HU  310
#define ST3_PU  340
#define NSLOT 290
#define NSTAT 410
#define L2OFF 160       // stage-2 stat range starts at 160

__device__ __forceinline__ float2 ld2(const float* p) { return *(const float2*)p; }

__device__ __forceinline__ float2 bnrelu2(float2 v, float sc, float sh) {
    float2 r;
    r.x = fmaf(v.x, sc, sh); r.y = fmaf(v.y, sc, sh);
    r.x = r.x > 0.f ? r.x : 0.f;
    r.y = r.y > 0.f ? r.y : 0.f;
    return r;
}

// ---------------------------------------------------------------------------
// Stage the block's weight slice into LDS (row-major, rows padded to CINP
// floats so every 8-channel chunk is 16B-aligned for ds_read_b128 broadcast).
// Replaces the old per-chunk scalar-cache weight reloads (s_load + lgkmcnt
// serialization) that capped VALUBusy at ~18%.
// ---------------------------------------------------------------------------
template<int CIN, int CINP, int COUT>
__device__ __forceinline__ void stage_w(const float* __restrict__ w, float* wl)
{
    if (CIN == CINP) {
        for (int idx = threadIdx.x; idx < COUT * CIN; idx += 256)
            wl[idx] = w[idx];
    } else {
        for (int idx = threadIdx.x; idx < COUT * CIN; idx += 256) {
            int o = idx / CIN;
            int c = idx - o * CIN;
            wl[o * CINP + c] = w[idx];
        }
    }
    __syncthreads();
}

__device__ __forceinline__ void fma8(float2& a, float4 w0, float4 w1,
                                     const float2* buf)
{
    a.x = fmaf(w0.x, buf[0].x, a.x); a.y = fmaf(w0.x, buf[0].y, a.y);
    a.x = fmaf(w0.y, buf[1].x, a.x); a.y = fmaf(w0.y, buf[1].y, a.y);
    a.x = fmaf(w0.z, buf[2].x, a.x); a.y = fmaf(w0.z, buf[2].y, a.y);
    a.x = fmaf(w0.w, buf[3].x, a.x); a.y = fmaf(w0.w, buf[3].y, a.y);
    a.x = fmaf(w1.x, buf[4].x, a.x); a.y = fmaf(w1.x, buf[4].y, a.y);
    a.x = fmaf(w1.y, buf[5].x, a.x); a.y = fmaf(w1.y, buf[5].y, a.y);
    a.x = fmaf(w1.z, buf[6].x, a.x); a.y = fmaf(w1.z, buf[6].y, a.y);
    a.x = fmaf(w1.w, buf[7].x, a.x); a.y = fmaf(w1.w, buf[7].y, a.y);
}

// ---------------------------------------------------------------------------
// Per-position conv + stats. Each thread owns TWO positions (float2).
// Software-pipelined CHUNK-channel loop; weights come from LDS via broadcast
// ds_read_b128 (all lanes same address -> conflict-free).
// Accumulation order per output channel is unchanged (c-ascending).
// ---------------------------------------------------------------------------
template<int CIN, int CINP, int COUT, class F>
__device__ __forceinline__ void conv2(F fetch, const float* wl,
                                      float* __restrict__ y, int p,
                                      float* __restrict__ sumA,
                                      float* __restrict__ sumqA,
                                      int stat0, float* red)
{
    constexpr int CHUNK = 8;
    float2 acc[COUT];
#pragma unroll
    for (int o = 0; o < COUT; ++o) acc[o] = make_float2(0.f, 0.f);

    constexpr int MAIN = (CIN / CHUNK) * CHUNK;
    if (MAIN > 0) {
        float2 buf[CHUNK];
#pragma unroll
        for (int i = 0; i < CHUNK; ++i) buf[i] = fetch(i);
#pragma unroll 1
        for (int c0 = CHUNK; c0 < MAIN; c0 += CHUNK) {
            float2 nxt[CHUNK];
#pragma unroll
            for (int i = 0; i < CHUNK; ++i) nxt[i] = fetch(c0 + i);  // prefetch
            const float* wb = wl + (c0 - CHUNK);
#pragma unroll
            for (int o = 0; o < COUT; ++o) {
                float4 w0 = *(const float4*)(wb + o * CINP);
                float4 w1 = *(const float4*)(wb + o * CINP + 4);
                fma8(acc[o], w0, w1, buf);
            }
#pragma unroll
            for (int i = 0; i < CHUNK; ++i) buf[i] = nxt[i];
        }
        const float* wb = wl + (MAIN - CHUNK);
#pragma unroll
        for (int o = 0; o < COUT; ++o) {           // drain last main chunk
            float4 w0 = *(const float4*)(wb + o * CINP);
            float4 w1 = *(const float4*)(wb + o * CINP + 4);
            fma8(acc[o], w0, w1, buf);
        }
    }
#pragma unroll
    for (int c = MAIN; c < CIN; ++c) {             // tail channels
        float2 x = fetch(c);
#pragma unroll
        for (int o = 0; o < COUT; ++o) {
            float wv = wl[o * CINP + c];
            acc[o].x = fmaf(wv, x.x, acc[o].x);
            acc[o].y = fmaf(wv, x.y, acc[o].y);
        }
    }

#pragma unroll
    for (int o = 0; o < COUT; ++o)
        *(float2*)(y + (size_t)o * NPOS + p) = acc[o];

    int lane = threadIdx.x & 63;
    int wv_  = threadIdx.x >> 6;
#pragma unroll
    for (int o = 0; o < COUT; ++o) {
        float s = acc[o].x + acc[o].y;
        float q = acc[o].x * acc[o].x + acc[o].y * acc[o].y;
#pragma unroll
        for (int i = 1; i < 64; i <<= 1) {
            s += __shfl_xor(s, i, 64);
            q += __shfl_xor(q, i, 64);
        }
        if (lane == 0) {
            red[(wv_ * COUT + o) * 2]     = s;
            red[(wv_ * COUT + o) * 2 + 1] = q;
        }
    }
    __syncthreads();
    if (threadIdx.x < COUT) {
        int o = threadIdx.x;
        float s = 0.f, q = 0.f;
#pragma unroll
        for (int k = 0; k < 4; ++k) {
            s += red[(k * COUT + o) * 2];
            q += red[(k * COUT + o) * 2 + 1];
        }
        atomicAdd(&sumA[stat0 + o], s);
        atomicAdd(&sumqA[stat0 + o], q);
    }
}

// ---------------------------------------------------------------------------
// Stage 1: hf1, fd1(x2), phu1, phl1, hd1(x2)
// ---------------------------------------------------------------------------
__global__ void __launch_bounds__(256) stage1_kernel(
    const float* __restrict__ xp, const float* __restrict__ xh,
    const float* __restrict__ xf, const float* __restrict__ p_fea,
    const float* __restrict__ h_fea,
    const float* __restrict__ w_hf1, const float* __restrict__ w_fd1,
    const float* __restrict__ w_phu1, const float* __restrict__ w_phl1,
    const float* __restrict__ w_hd1, float* __restrict__ ws)
{
    __shared__ __align__(16) float wlds[35 * 276];   // max slice: hd1
    __shared__ float red[4 * 40 * 2];
    int g = blockIdx.x * 256 + threadIdx.x;
    int p = g * 2;
    int b = (p >= HW) ? 1 : 0;
    int s = p - b * HW;
    float* y     = ws;
    float* sumA  = ws + (size_t)NSLOT * NPOS;
    float* sumqA = sumA + NSTAT;

    switch (blockIdx.y) {
    case 0: { // hf1: [xh1; xh2] (20) -> 20
        stage_w<20, 20, 20>(w_hf1, wlds);
        const float* xb = xh + ((size_t)b * 30 + 10) * HW + s;
        conv2<20, 20, 20>([&](int c) { return ld2(xb + c * HW); },
                      wlds, y + (size_t)S1_HF1 * NPOS, p, sumA, sumqA, S1_HF1, red);
        break; }
    case 1: case 2: { // fd1: [h_fea; xf1] (266) -> 15+15
        int off = (blockIdx.y - 1) * 15;
        stage_w<266, 268, 15>(w_fd1 + off * 266, wlds);
        const float* hb  = h_fea + (size_t)b * 256 * HW + s;
        const float* xf1 = xf + ((size_t)b * 20 + 10) * HW + s;
        conv2<266, 268, 15>([&](int c) { return (c < 256) ? ld2(hb + c * HW)
                                                          : ld2(xf1 + (c - 256) * HW); },
                       wlds, y + (size_t)(S1_FD1 + off) * NPOS, p,
                       sumA, sumqA, S1_FD1 + off, red);
        break; }
    case 3: { // phu1: xp[1:5] (40) -> 20
        stage_w<40, 40, 20>(w_phu1, wlds);
        const float* xb = xp + ((size_t)b * 70 + 10) * HW + s;
        conv2<40, 40, 20>([&](int c) { return ld2(xb + c * HW); },
                      wlds, y + (size_t)S1_PHU1 * NPOS, p, sumA, sumqA, S1_PHU1, red);
        break; }
    case 4: { // phl1: xp[5:7] (20) -> 20
        stage_w<20, 20, 20>(w_phl1, wlds);
        const float* xb = xp + ((size_t)b * 70 + 50) * HW + s;
        conv2<20, 20, 20>([&](int c) { return ld2(xb + c * HW); },
                      wlds, y + (size_t)S1_PHL1 * NPOS, p, sumA, sumqA, S1_PHL1, red);
        break; }
    default: { // hd1: [p_fea; xh1; xh2] (276) -> 35+35
        int off = (blockIdx.y - 5) * 35;
        stage_w<276, 276, 35>(w_hd1 + off * 276, wlds);
        const float* pb = p_fea + (size_t)b * 256 * HW + s;
        const float* xb = xh + ((size_t)b * 30 + 10) * HW + s;
        conv2<276, 276, 35>([&](int c) { return (c < 256) ? ld2(pb + c * HW)
                                                          : ld2(xb + (c - 256) * HW); },
                       wlds, y + (size_t)(S1_HD1 + off) * NPOS, p,
                       sumA, sumqA, S1_HD1 + off, red);
        break; }
    }
}

// ---------------------------------------------------------------------------
// scale/shift from accumulated stats
// ---------------------------------------------------------------------------
__global__ void scale_kernel(int stage,
    const float* __restrict__ bn_hf1, const float* __restrict__ bn_hf2,
    const float* __restrict__ bn_phu1, const float* __restrict__ bn_phu2,
    const float* __restrict__ bn_phl1, const float* __restrict__ bn_phl2,
    const float* __restrict__ bn_fd1, const float* __restrict__ bn_fd2,
    const float* __restrict__ bn_hd1, const float* __restrict__ bn_hd2,
    const float* __restrict__ bn_fu, const float* __restrict__ bn_hu,
    const float* __restrict__ bn_pu, float* __restrict__ ws)
{
    int t = threadIdx.x;
    float* sumA   = ws + (size_t)NSLOT * NPOS;
    float* sumqA  = sumA + NSTAT;
    float* scaleA = sumqA + NSTAT;
    float* shiftA = scaleA + NSTAT;
    int stat, local, co;
    const float* bn;
    if (stage == 1) {
        if (t >= 160) return;
        stat = t;
        if      (t < 20) { bn = bn_hf1;  local = t;      co = 20; }
        else if (t < 50) { bn = bn_fd1;  local = t - 20; co = 30; }
        else if (t < 70) { bn = bn_phu1; local = t - 50; co = 20; }
        else if (t < 90) { bn = bn_phl1; local = t - 70; co = 20; }
        else             { bn = bn_hd1;  local = t - 90; co = 70; }
    } else if (stage == 2) {
        if (t >= 130) return;
        stat = 160 + t;
        if      (t < 10) { bn = bn_hf2;  local = t;      co = 10; }
        else if (t < 40) { bn = bn_fd2;  local = t - 10; co = 30; }
        else if (t < 50) { bn = bn_phu2; local = t - 40; co = 10; }
        else if (t < 60) { bn = bn_phl2; local = t - 50; co = 10; }
        else             { bn = bn_hd2;  local = t - 60; co = 70; }
    } else {
        if (t >= 120) return;
        stat = 290 + t;
        if      (t < 20) { bn = bn_fu; local = t;      co = 20; }
        else if (t < 50) { bn = bn_hu; local = t - 20; co = 30; }
        else             { bn = bn_pu; local = t - 50; co = 70; }
    }
    float n  = (float)NPOS;
    float m  = sumA[stat] / n;
    float v  = sumqA[stat] / n - m * m;
    float g  = bn[local];
    float bt = bn[co + local];
    float sc = g * rsqrtf(v + EPSV);
    scaleA[stat] = sc;
    shiftA[stat] = bt - m * sc;
}

// ---------------------------------------------------------------------------
// Stage 2: hf2, fd2, phu2, phl2, hd2(x2)  (bn+relu stage-1 on the fly)
// ---------------------------------------------------------------------------
__global__ void __launch_bounds__(256) stage2_kernel(
    const float* __restrict__ w_hf2, const float* __restrict__ w_fd2,
    const float* __restrict__ w_phu2, const float* __restrict__ w_phl2,
    const float* __restrict__ w_hd2, float* __restrict__ ws)
{
    __shared__ __align__(16) float wlds[35 * 72];    // max slice: hd2
    __shared__ float red[4 * 40 * 2];
    __shared__ float ssc[160], ssh[160];
    int g = blockIdx.x * 256 + threadIdx.x;
    int p = g * 2;
    float* y     = ws;
    float* sumA  = ws + (size_t)NSLOT * NPOS;
    float* sumqA = sumA + NSTAT;
    const float* scaleA = sumqA + NSTAT;
    const float* shiftA = scaleA + NSTAT;

    // stage-1 scale/shift -> LDS (kills per-channel uniform global loads)
    for (int i = threadIdx.x; i < 160; i += 256) { ssc[i] = scaleA[i]; ssh[i] = shiftA[i]; }

    switch (blockIdx.y) {
    case 0: { // hf2: hf1(20) -> 10
        stage_w<20, 20, 10>(w_hf2, wlds);
        const float* src = y + (size_t)S1_HF1 * NPOS + p;
        conv2<20, 20, 10>([&](int c) {
            return bnrelu2(ld2(src + (size_t)c * NPOS), ssc[S1_HF1 + c], ssh[S1_HF1 + c]); },
            wlds, y + (size_t)S2_HF2 * NPOS, p, sumA, sumqA, S2_HF2, red);
        break; }
    case 1: { // fd2: fd1(30) -> 30
        stage_w<30, 32, 30>(w_fd2, wlds);
        const float* src = y + (size_t)S1_FD1 * NPOS + p;
        conv2<30, 32, 30>([&](int c) {
            return bnrelu2(ld2(src + (size_t)c * NPOS), ssc[S1_FD1 + c], ssh[S1_FD1 + c]); },
            wlds, y + (size_t)S2_FD2 * NPOS, p, sumA, sumqA, S2_FD2, red);
        break; }
    case 2: { // phu2: phu1(20) -> 10
        stage_w<20, 20, 10>(w_phu2, wlds);
        const float* src = y + (size_t)S1_PHU1 * NPOS + p;
        conv2<20, 20, 10>([&](int c) {
            return bnrelu2(ld2(src + (size_t)c * NPOS), ssc[S1_PHU1 + c], ssh[S1_PHU1 + c]); },
            wlds, y + (size_t)S2_PHU2 * NPOS, p, sumA, sumqA, S2_PHU2, red);
        break; }
    case 3: { // phl2: phl1(20) -> 10
        stage_w<20, 20, 10>(w_phl2, wlds);
        const float* src = y + (size_t)S1_PHL1 * NPOS + p;
        conv2<20, 20, 10>([&](int c) {
            return bnrelu2(ld2(src + (size_t)c * NPOS), ssc[S1_PHL1 + c], ssh[S1_PHL1 + c]); },
            wlds, y + (size_t)S2_PHL2 * NPOS, p, sumA, sumqA, S2_PHL2, red);
        break; }
    default: { // hd2: hd1(70) -> 35+35
        int off = (blockIdx.y - 4) * 35;
        stage_w<70, 72, 35>(w_hd2 + off * 70, wlds);
        const float* src = y + (size_t)S1_HD1 * NPOS + p;
        conv2<70, 72, 35>([&](int c) {
            return bnrelu2(ld2(src + (size_t)c * NPOS), ssc[S1_HD1 + c], ssh[S1_HD1 + c]); },
            wlds, y + (size_t)(S2_HD2 + off) * NPOS, p,
            sumA, sumqA, S2_HD2 + off, red);
        break; }
    }
}

// ---------------------------------------------------------------------------
// Stage 3: fu, hu, pu(x2)
// ---------------------------------------------------------------------------
__global__ void __launch_bounds__(256) stage3_kernel(
    const float* __restrict__ xp, const float* __restrict__ xh,
    const float* __restrict__ xf, const float* __restrict__ p_fea,
    const float* __restrict__ h_fea, const float* __restrict__ f_fea,
    const float* __restrict__ w_fu, const float* __restrict__ w_hu,
    const float* __restrict__ w_pu, float* __restrict__ ws)
{
    __shared__ __align__(16) float wlds[35 * 316];   // max slice: pu
    __shared__ float red[4 * 40 * 2];
    __shared__ float ssc[130], ssh[130];             // stage-2 stat range
    int g = blockIdx.x * 256 + threadIdx.x;
    int p = g * 2;
    int b = (p >= HW) ? 1 : 0;
    int s = p - b * HW;
    float* y     = ws;
    float* sumA  = ws + (size_t)NSLOT * NPOS;
    float* sumqA = sumA + NSTAT;
    const float* scaleA = sumqA + NSTAT;
    const float* shiftA = scaleA + NSTAT;

    for (int i = threadIdx.x; i < 130; i += 256) {
        ssc[i] = scaleA[L2OFF + i]; ssh[i] = shiftA[L2OFF + i];
    }

    switch (blockIdx.y) {
    case 0: { // fu: [f_fea; xf_new] (266) -> 20 ; xf_new = bnrelu(hf2) + xf1
        stage_w<266, 268, 20>(w_fu, wlds);
        const float* fb   = f_fea + (size_t)b * 256 * HW + s;
        const float* yhf2 = y + (size_t)S2_HF2 * NPOS + p;
        const float* xf1  = xf + ((size_t)b * 20 + 10) * HW + s;
        conv2<266, 268, 20>([&](int c) {
            if (c < 256) return ld2(fb + c * HW);
            int cc = c - 256;
            float2 v = bnrelu2(ld2(yhf2 + (size_t)cc * NPOS),
                               ssc[S2_HF2 - L2OFF + cc], ssh[S2_HF2 - L2OFF + cc]);
            float2 r0 = ld2(xf1 + cc * HW);
            return make_float2(v.x + r0.x, v.y + r0.y); },
            wlds, y + (size_t)S3_FU * NPOS, p, sumA, sumqA, ST3_FU, red);
        break; }
    case 1: { // hu: [h_fea; xhu; xhl] (276) -> 30
        stage_w<276, 276, 30>(w_hu, wlds);
        const float* hb    = h_fea + (size_t)b * 256 * HW + s;
        const float* yphu2 = y + (size_t)S2_PHU2 * NPOS + p;
        const float* yphl2 = y + (size_t)S2_PHL2 * NPOS + p;
        const float* yfd2  = y + (size_t)S2_FD2 * NPOS + p;
        const float* xh1b  = xh + ((size_t)b * 30 + 10) * HW + s;
        conv2<276, 276, 30>([&](int c) {
            if (c < 256) return ld2(hb + c * HW);
            if (c < 266) {
                int cc = c - 256;
                float2 a = bnrelu2(ld2(yphu2 + (size_t)cc * NPOS),
                                   ssc[S2_PHU2 - L2OFF + cc], ssh[S2_PHU2 - L2OFF + cc]);
                float2 f = bnrelu2(ld2(yfd2 + (size_t)(10 + cc) * NPOS),
                                   ssc[S2_FD2 - L2OFF + 10 + cc], ssh[S2_FD2 - L2OFF + 10 + cc]);
                float2 r0 = ld2(xh1b + cc * HW);
                return make_float2(r0.x + a.x + f.x, r0.y + a.y + f.y);
            }
            int cc = c - 266;
            float2 a = bnrelu2(ld2(yphl2 + (size_t)cc * NPOS),
                               ssc[S2_PHL2 - L2OFF + cc], ssh[S2_PHL2 - L2OFF + cc]);
            float2 f = bnrelu2(ld2(yfd2 + (size_t)(20 + cc) * NPOS),
                               ssc[S2_FD2 - L2OFF + 20 + cc], ssh[S2_FD2 - L2OFF + 20 + cc]);
            float2 r0 = ld2(xh1b + (10 + cc) * HW);
            return make_float2(r0.x + a.x + f.x, r0.y + a.y + f.y); },
            wlds, y + (size_t)S3_HU * NPOS, p, sumA, sumqA, ST3_HU, red);
        break; }
    default: { // pu: [p_fea; xp_new(60)] (316) -> 35+35
        int off = (blockIdx.y - 2) * 35;
        stage_w<316, 316, 35>(w_pu + off * 316, wlds);
        const float* pb   = p_fea + (size_t)b * 256 * HW + s;
        const float* yhd2 = y + (size_t)S2_HD2 * NPOS + p;
        const float* xpb  = xp + ((size_t)b * 70 + 10) * HW + s;
        conv2<316, 316, 35>([&](int c) {
            if (c < 256) return ld2(pb + c * HW);
            int cc = c - 256;
            float2 v = bnrelu2(ld2(yhd2 + (size_t)(10 + cc) * NPOS),
                               ssc[S2_HD2 - L2OFF + 10 + cc], ssh[S2_HD2 - L2OFF + 10 + cc]);
            float2 r0 = ld2(xpb + cc * HW);
            return make_float2(v.x + r0.x, v.y + r0.y); },
            wlds, y + (size_t)(S3_PU + off) * NPOS, p,
            sumA, sumqA, ST3_PU + off, red);
        break; }
    }
}

// ---------------------------------------------------------------------------
// Final: bn+relu all 220 output channels, float4
// out = concat([xp_upd(70), xh_upd(30), xf_upd(20), xfh(30), xhp(70)])
// ---------------------------------------------------------------------------
__global__ void __launch_bounds__(256) final_kernel(const float* __restrict__ ws,
                                                    float* __restrict__ out)
{
    int g = blockIdx.x * 256 + threadIdx.x;
    int p = g * 4;
    int c = blockIdx.y;
    const float* sumA   = ws + (size_t)NSLOT * NPOS;
    const float* scaleA = sumA + 2 * NSTAT;
    const float* shiftA = scaleA + NSTAT;
    int slot, stat;
    if      (c < 70)  { slot = S3_PU  + c;         stat = ST3_PU  + c;         }
    else if (c < 100) { slot = S3_HU  + (c - 70);  stat = ST3_HU  + (c - 70);  }
    else if (c < 120) { slot = S3_FU  + (c - 100); stat = ST3_FU  + (c - 100); }
    else if (c < 150) { slot = S2_FD2 + (c - 120); stat = S2_FD2 + (c - 120);  }
    else              { slot = S2_HD2 + (c - 150); stat = S2_HD2 + (c - 150);  }
    float4 v = *(const float4*)(ws + (size_t)slot * NPOS + p);
    float sc = scaleA[stat], sh = shiftA[stat];
    v.x = fmaf(v.x, sc, sh); v.x = v.x > 0.f ? v.x : 0.f;
    v.y = fmaf(v.y, sc, sh); v.y = v.y > 0.f ? v.y : 0.f;
    v.z = fmaf(v.z, sc, sh); v.z = v.z > 0.f ? v.z : 0.f;
    v.w = fmaf(v.w, sc, sh); v.w = v.w > 0.f ? v.w : 0.f;
    int b = (p >= HW) ? 1 : 0;
    int s = p - b * HW;
    *(float4*)(out + ((size_t)b * 220 + c) * HW + s) = v;
}

// ---------------------------------------------------------------------------
extern "C" void kernel_launch(void* const* d_in, const int* in_sizes, int n_in,
                              void* d_out, int out_size, void* d_ws, size_t ws_size,
                              hipStream_t stream)
{
    const float* xp     = (const float*)d_in[0];
    const float* xh     = (const float*)d_in[1];
    const float* xf     = (const float*)d_in[2];
    const float* p_fea  = (const float*)d_in[3];
    const float* h_fea  = (const float*)d_in[4];
    const float* f_fea  = (const float*)d_in[5];
    const float* w_hf1  = (const float*)d_in[6];  const float* bn_hf1  = (const float*)d_in[7];
    const float* w_hf2  = (const float*)d_in[8];  const float* bn_hf2  = (const float*)d_in[9];
    const float* w_phu1 = (const float*)d_in[10]; const float* bn_phu1 = (const float*)d_in[11];
    const float* w_phu2 = (const float*)d_in[12]; const float* bn_phu2 = (const float*)d_in[13];
    const float* w_phl1 = (const float*)d_in[14]; const float* bn_phl1 = (const float*)d_in[15];
    const float* w_phl2 = (const float*)d_in[16]; const float* bn_phl2 = (const float*)d_in[17];
    const float* w_fd1  = (const float*)d_in[18]; const float* bn_fd1  = (const float*)d_in[19];
    const float* w_fd2  = (const float*)d_in[20]; const float* bn_fd2  = (const float*)d_in[21];
    const float* w_hd1  = (const float*)d_in[22]; const float* bn_hd1  = (const float*)d_in[23];
    const float* w_hd2  = (const float*)d_in[24]; const float* bn_hd2  = (const float*)d_in[25];
    const float* w_fu   = (const float*)d_in[26]; const float* bn_fu   = (const float*)d_in[27];
    const float* w_hu   = (const float*)d_in[28]; const float* bn_hu   = (const float*)d_in[29];
    const float* w_pu   = (const float*)d_in[30]; const float* bn_pu   = (const float*)d_in[31];

    float* ws  = (float*)d_ws;
    float* out = (float*)d_out;

    size_t need_bytes = ((size_t)NSLOT * NPOS + 4 * NSTAT) * sizeof(float);
    if (ws_size < need_bytes) return;

    hipMemsetAsync(ws + (size_t)NSLOT * NPOS, 0, 2 * NSTAT * sizeof(float), stream);

    dim3 blk(256);
    const int GX = NPOS / 512;   // 144 blocks, 2 positions/thread
    stage1_kernel<<<dim3(GX, 7), blk, 0, stream>>>(xp, xh, xf, p_fea, h_fea,
                                                   w_hf1, w_fd1, w_phu1, w_phl1, w_hd1, ws);
    scale_kernel<<<1, 256, 0, stream>>>(1, bn_hf1, bn_hf2, bn_phu1, bn_phu2, bn_phl1, bn_phl2,
                                        bn_fd1, bn_fd2, bn_hd1, bn_hd2, bn_fu, bn_hu, bn_pu, ws);
    stage2_kernel<<<dim3(GX, 6), blk, 0, stream>>>(w_hf2, w_fd2, w_phu2, w_phl2, w_hd2, ws);
    scale_kernel<<<1, 256, 0, stream>>>(2, bn_hf1, bn_hf2, bn_phu1, bn_phu2, bn_phl1, bn_phl2,
                                        bn_fd1, bn_fd2, bn_hd1, bn_hd2, bn_fu, bn_hu, bn_pu, ws);
    stage3_kernel<<<dim3(GX, 4), blk, 0, stream>>>(xp, xh, xf, p_fea, h_fea, f_fea,
                                                   w_fu, w_hu, w_pu, ws);
    scale_kernel<<<1, 256, 0, stream>>>(3, bn_hf1, bn_hf2, bn_phu1, bn_phu2, bn_phl1, bn_phl2,
                                        bn_fd1, bn_fd2, bn_hd1, bn_hd2, bn_fu, bn_hu, bn_pu, ws);
    final_kernel<<<dim3(NPOS / 1024, 220), blk, 0, stream>>>(ws, out);
}

// Round 2
// 626.246 us; speedup vs baseline: 1.2136x; 1.2136x over previous
//
#include <hip/hip_runtime.h>

#define HW   36864      // 192*192
#define NPOS 73728      // B*HW, B=2
#define EPSV 1e-5f

// channel-slot layout in workspace (each slot = NPOS floats)
#define S1_HF1  0
#define S1_FD1  20
#define S1_PHU1 50
#define S1_PHL1 70
#define S1_HD1  90
#define S2_HF2  160
#define S2_FD2  170
#define S2_PHU2 200
#define S2_PHL2 210
#define S2_HD2  220
#define S3_FU   0       // reuse stage-1 slots (dead by stage 3)
#define S3_HU   20
#define S3_PU   50
#define ST3_FU  290     // stat-channel bases for stage 3
#define ST3_HU  310
#define ST3_PU  340
#define NSLOT 290
#define NSTAT 410
#define L2OFF 160       // stage-2 stat range starts at 160

#define MT 10           // output channels per block (COUT slice)

__device__ __forceinline__ float4 ld4(const float* p) { return *(const float4*)p; }

__device__ __forceinline__ float4 bnrelu4(float4 v, float sc, float sh) {
    float4 r;
    r.x = fmaf(v.x, sc, sh); r.y = fmaf(v.y, sc, sh);
    r.z = fmaf(v.z, sc, sh); r.w = fmaf(v.w, sc, sh);
    r.x = r.x > 0.f ? r.x : 0.f;
    r.y = r.y > 0.f ? r.y : 0.f;
    r.z = r.z > 0.f ? r.z : 0.f;
    r.w = r.w > 0.f ? r.w : 0.f;
    return r;
}

// ---------------------------------------------------------------------------
// Stage this block's MT-row weight slice into LDS, rows padded to CINP floats
// (multiple of 4) so per-chunk reads are single broadcast ds_read_b128.
// ---------------------------------------------------------------------------
template<int CIN, int CINP>
__device__ __forceinline__ void stage_w(const float* __restrict__ w, float* wl)
{
    if (CIN == CINP) {
        for (int idx = threadIdx.x; idx < MT * CIN; idx += 256)
            wl[idx] = w[idx];
    } else {
        for (int idx = threadIdx.x; idx < MT * CIN; idx += 256) {
            int o = idx / CIN;
            int c = idx - o * CIN;
            wl[o * CINP + c] = w[idx];
        }
    }
    __syncthreads();
}

// 4 channels x 4 positions for one output channel: 16 fmaf, channel-ascending
__device__ __forceinline__ void fma4x4(float4& a, float4 w, const float4* buf)
{
    a.x = fmaf(w.x, buf[0].x, a.x); a.y = fmaf(w.x, buf[0].y, a.y);
    a.z = fmaf(w.x, buf[0].z, a.z); a.w = fmaf(w.x, buf[0].w, a.w);
    a.x = fmaf(w.y, buf[1].x, a.x); a.y = fmaf(w.y, buf[1].y, a.y);
    a.z = fmaf(w.y, buf[1].z, a.z); a.w = fmaf(w.y, buf[1].w, a.w);
    a.x = fmaf(w.z, buf[2].x, a.x); a.y = fmaf(w.z, buf[2].y, a.y);
    a.z = fmaf(w.z, buf[2].z, a.z); a.w = fmaf(w.z, buf[2].w, a.w);
    a.x = fmaf(w.w, buf[3].x, a.x); a.y = fmaf(w.w, buf[3].y, a.y);
    a.z = fmaf(w.w, buf[3].z, a.z); a.w = fmaf(w.w, buf[3].w, a.w);
}

// ---------------------------------------------------------------------------
// Register-tiled conv slice: each thread owns FOUR positions (float4), block
// computes MT=10 output channels. Software-pipelined 4-channel chunks;
// weights broadcast from LDS (same-addr ds_read_b128, conflict-free).
// Per-position accumulation order is channel-ascending (matches reference).
// ---------------------------------------------------------------------------
template<int CIN, int CINP, class F>
__device__ __forceinline__ void conv4(F fetch, const float* wl,
                                      float* __restrict__ y, int p,
                                      float* __restrict__ sumA,
                                      float* __restrict__ sumqA,
                                      int stat0, float* red)
{
    float4 acc[MT];
#pragma unroll
    for (int o = 0; o < MT; ++o) acc[o] = make_float4(0.f, 0.f, 0.f, 0.f);

    constexpr int MAIN = (CIN / 4) * 4;
    if (MAIN > 0) {
        float4 buf[4];
#pragma unroll
        for (int i = 0; i < 4; ++i) buf[i] = fetch(i);
#pragma unroll 1
        for (int c0 = 4; c0 < MAIN; c0 += 4) {
            float4 nxt[4];
#pragma unroll
            for (int i = 0; i < 4; ++i) nxt[i] = fetch(c0 + i);   // prefetch
            const float* wb = wl + (c0 - 4);
#pragma unroll
            for (int o = 0; o < MT; ++o)
                fma4x4(acc[o], *(const float4*)(wb + o * CINP), buf);
#pragma unroll
            for (int i = 0; i < 4; ++i) buf[i] = nxt[i];
        }
        const float* wb = wl + (MAIN - 4);
#pragma unroll
        for (int o = 0; o < MT; ++o)                  // drain last chunk
            fma4x4(acc[o], *(const float4*)(wb + o * CINP), buf);
    }
#pragma unroll
    for (int c = MAIN; c < CIN; ++c) {                // tail channels
        float4 x = fetch(c);
#pragma unroll
        for (int o = 0; o < MT; ++o) {
            float wv = wl[o * CINP + c];
            acc[o].x = fmaf(wv, x.x, acc[o].x);
            acc[o].y = fmaf(wv, x.y, acc[o].y);
            acc[o].z = fmaf(wv, x.z, acc[o].z);
            acc[o].w = fmaf(wv, x.w, acc[o].w);
        }
    }

#pragma unroll
    for (int o = 0; o < MT; ++o)
        *(float4*)(y + (size_t)o * NPOS + p) = acc[o];

    int lane = threadIdx.x & 63;
    int wv_  = threadIdx.x >> 6;
#pragma unroll
    for (int o = 0; o < MT; ++o) {
        float s = (acc[o].x + acc[o].y) + (acc[o].z + acc[o].w);
        float q = (acc[o].x * acc[o].x + acc[o].y * acc[o].y)
                + (acc[o].z * acc[o].z + acc[o].w * acc[o].w);
#pragma unroll
        for (int i = 1; i < 64; i <<= 1) {
            s += __shfl_xor(s, i, 64);
            q += __shfl_xor(q, i, 64);
        }
        if (lane == 0) {
            red[(wv_ * MT + o) * 2]     = s;
            red[(wv_ * MT + o) * 2 + 1] = q;
        }
    }
    __syncthreads();
    if (threadIdx.x < MT) {
        int o = threadIdx.x;
        float s = 0.f, q = 0.f;
#pragma unroll
        for (int k = 0; k < 4; ++k) {
            s += red[(k * MT + o) * 2];
            q += red[(k * MT + o) * 2 + 1];
        }
        atomicAdd(&sumA[stat0 + o], s);
        atomicAdd(&sumqA[stat0 + o], q);
    }
}

// ---------------------------------------------------------------------------
// Stage 1: hf1(2), fd1(3), phu1(2), phl1(2), hd1(7)  -> blockIdx.y in [0,16)
// ---------------------------------------------------------------------------
__global__ void __launch_bounds__(256) stage1_kernel(
    const float* __restrict__ xp, const float* __restrict__ xh,
    const float* __restrict__ xf, const float* __restrict__ p_fea,
    const float* __restrict__ h_fea,
    const float* __restrict__ w_hf1, const float* __restrict__ w_fd1,
    const float* __restrict__ w_phu1, const float* __restrict__ w_phl1,
    const float* __restrict__ w_hd1, float* __restrict__ ws)
{
    __shared__ __align__(16) float wlds[MT * 276];
    __shared__ float red[4 * MT * 2];
    int g = blockIdx.x * 256 + threadIdx.x;
    int p = g * 4;
    int b = (p >= HW) ? 1 : 0;
    int s = p - b * HW;
    float* y     = ws;
    float* sumA  = ws + (size_t)NSLOT * NPOS;
    float* sumqA = sumA + NSTAT;
    int yb = blockIdx.y;

    if (yb < 2) {            // hf1: [xh1; xh2] (20) -> 10+10
        int off = yb * MT;
        stage_w<20, 20>(w_hf1 + off * 20, wlds);
        const float* xb = xh + ((size_t)b * 30 + 10) * HW + s;
        conv4<20, 20>([&](int c) { return ld4(xb + c * HW); },
                      wlds, y + (size_t)(S1_HF1 + off) * NPOS, p,
                      sumA, sumqA, S1_HF1 + off, red);
    } else if (yb < 5) {     // fd1: [h_fea; xf1] (266) -> 3 x 10
        int off = (yb - 2) * MT;
        stage_w<266, 268>(w_fd1 + off * 266, wlds);
        const float* hb  = h_fea + (size_t)b * 256 * HW + s;
        const float* xf1 = xf + ((size_t)b * 20 + 10) * HW + s;
        conv4<266, 268>([&](int c) { return (c < 256) ? ld4(hb + c * HW)
                                                      : ld4(xf1 + (c - 256) * HW); },
                        wlds, y + (size_t)(S1_FD1 + off) * NPOS, p,
                        sumA, sumqA, S1_FD1 + off, red);
    } else if (yb < 7) {     // phu1: xp[1:5] (40) -> 10+10
        int off = (yb - 5) * MT;
        stage_w<40, 40>(w_phu1 + off * 40, wlds);
        const float* xb = xp + ((size_t)b * 70 + 10) * HW + s;
        conv4<40, 40>([&](int c) { return ld4(xb + c * HW); },
                      wlds, y + (size_t)(S1_PHU1 + off) * NPOS, p,
                      sumA, sumqA, S1_PHU1 + off, red);
    } else if (yb < 9) {     // phl1: xp[5:7] (20) -> 10+10
        int off = (yb - 7) * MT;
        stage_w<20, 20>(w_phl1 + off * 20, wlds);
        const float* xb = xp + ((size_t)b * 70 + 50) * HW + s;
        conv4<20, 20>([&](int c) { return ld4(xb + c * HW); },
                      wlds, y + (size_t)(S1_PHL1 + off) * NPOS, p,
                      sumA, sumqA, S1_PHL1 + off, red);
    } else {                 // hd1: [p_fea; xh1; xh2] (276) -> 7 x 10
        int off = (yb - 9) * MT;
        stage_w<276, 276>(w_hd1 + off * 276, wlds);
        const float* pb = p_fea + (size_t)b * 256 * HW + s;
        const float* xb = xh + ((size_t)b * 30 + 10) * HW + s;
        conv4<276, 276>([&](int c) { return (c < 256) ? ld4(pb + c * HW)
                                                      : ld4(xb + (c - 256) * HW); },
                        wlds, y + (size_t)(S1_HD1 + off) * NPOS, p,
                        sumA, sumqA, S1_HD1 + off, red);
    }
}

// ---------------------------------------------------------------------------
// scale/shift from accumulated stats
// ---------------------------------------------------------------------------
__global__ void scale_kernel(int stage,
    const float* __restrict__ bn_hf1, const float* __restrict__ bn_hf2,
    const float* __restrict__ bn_phu1, const float* __restrict__ bn_phu2,
    const float* __restrict__ bn_phl1, const float* __restrict__ bn_phl2,
    const float* __restrict__ bn_fd1, const float* __restrict__ bn_fd2,
    const float* __restrict__ bn_hd1, const float* __restrict__ bn_hd2,
    const float* __restrict__ bn_fu, const float* __restrict__ bn_hu,
    const float* __restrict__ bn_pu, float* __restrict__ ws)
{
    int t = threadIdx.x;
    float* sumA   = ws + (size_t)NSLOT * NPOS;
    float* sumqA  = sumA + NSTAT;
    float* scaleA = sumqA + NSTAT;
    float* shiftA = scaleA + NSTAT;
    int stat, local, co;
    const float* bn;
    if (stage == 1) {
        if (t >= 160) return;
        stat = t;
        if      (t < 20) { bn = bn_hf1;  local = t;      co = 20; }
        else if (t < 50) { bn = bn_fd1;  local = t - 20; co = 30; }
        else if (t < 70) { bn = bn_phu1; local = t - 50; co = 20; }
        else if (t < 90) { bn = bn_phl1; local = t - 70; co = 20; }
        else             { bn = bn_hd1;  local = t - 90; co = 70; }
    } else if (stage == 2) {
        if (t >= 130) return;
        stat = 160 + t;
        if      (t < 10) { bn = bn_hf2;  local = t;      co = 10; }
        else if (t < 40) { bn = bn_fd2;  local = t - 10; co = 30; }
        else if (t < 50) { bn = bn_phu2; local = t - 40; co = 10; }
        else if (t < 60) { bn = bn_phl2; local = t - 50; co = 10; }
        else             { bn = bn_hd2;  local = t - 60; co = 70; }
    } else {
        if (t >= 120) return;
        stat = 290 + t;
        if      (t < 20) { bn = bn_fu; local = t;      co = 20; }
        else if (t < 50) { bn = bn_hu; local = t - 20; co = 30; }
        else             { bn = bn_pu; local = t - 50; co = 70; }
    }
    float n  = (float)NPOS;
    float m  = sumA[stat] / n;
    float v  = sumqA[stat] / n - m * m;
    float g  = bn[local];
    float bt = bn[co + local];
    float sc = g * rsqrtf(v + EPSV);
    scaleA[stat] = sc;
    shiftA[stat] = bt - m * sc;
}

// ---------------------------------------------------------------------------
// Stage 2: hf2(1), fd2(3), phu2(1), phl2(1), hd2(7) -> blockIdx.y in [0,13)
// ---------------------------------------------------------------------------
__global__ void __launch_bounds__(256) stage2_kernel(
    const float* __restrict__ w_hf2, const float* __restrict__ w_fd2,
    const float* __restrict__ w_phu2, const float* __restrict__ w_phl2,
    const float* __restrict__ w_hd2, float* __restrict__ ws)
{
    __shared__ __align__(16) float wlds[MT * 72];
    __shared__ float red[4 * MT * 2];
    __shared__ float ssc[160], ssh[160];
    int g = blockIdx.x * 256 + threadIdx.x;
    int p = g * 4;
    float* y     = ws;
    float* sumA  = ws + (size_t)NSLOT * NPOS;
    float* sumqA = sumA + NSTAT;
    const float* scaleA = sumqA + NSTAT;
    const float* shiftA = scaleA + NSTAT;

    for (int i = threadIdx.x; i < 160; i += 256) { ssc[i] = scaleA[i]; ssh[i] = shiftA[i]; }
    int yb = blockIdx.y;

    if (yb == 0) {           // hf2: hf1(20) -> 10
        stage_w<20, 20>(w_hf2, wlds);
        const float* src = y + (size_t)S1_HF1 * NPOS + p;
        conv4<20, 20>([&](int c) {
            return bnrelu4(ld4(src + (size_t)c * NPOS), ssc[S1_HF1 + c], ssh[S1_HF1 + c]); },
            wlds, y + (size_t)S2_HF2 * NPOS, p, sumA, sumqA, S2_HF2, red);
    } else if (yb < 4) {     // fd2: fd1(30) -> 3 x 10
        int off = (yb - 1) * MT;
        stage_w<30, 32>(w_fd2 + off * 30, wlds);
        const float* src = y + (size_t)S1_FD1 * NPOS + p;
        conv4<30, 32>([&](int c) {
            return bnrelu4(ld4(src + (size_t)c * NPOS), ssc[S1_FD1 + c], ssh[S1_FD1 + c]); },
            wlds, y + (size_t)(S2_FD2 + off) * NPOS, p, sumA, sumqA, S2_FD2 + off, red);
    } else if (yb == 4) {    // phu2: phu1(20) -> 10
        stage_w<20, 20>(w_phu2, wlds);
        const float* src = y + (size_t)S1_PHU1 * NPOS + p;
        conv4<20, 20>([&](int c) {
            return bnrelu4(ld4(src + (size_t)c * NPOS), ssc[S1_PHU1 + c], ssh[S1_PHU1 + c]); },
            wlds, y + (size_t)S2_PHU2 * NPOS, p, sumA, sumqA, S2_PHU2, red);
    } else if (yb == 5) {    // phl2: phl1(20) -> 10
        stage_w<20, 20>(w_phl2, wlds);
        const float* src = y + (size_t)S1_PHL1 * NPOS + p;
        conv4<20, 20>([&](int c) {
            return bnrelu4(ld4(src + (size_t)c * NPOS), ssc[S1_PHL1 + c], ssh[S1_PHL1 + c]); },
            wlds, y + (size_t)S2_PHL2 * NPOS, p, sumA, sumqA, S2_PHL2, red);
    } else {                 // hd2: hd1(70) -> 7 x 10
        int off = (yb - 6) * MT;
        stage_w<70, 72>(w_hd2 + off * 70, wlds);
        const float* src = y + (size_t)S1_HD1 * NPOS + p;
        conv4<70, 72>([&](int c) {
            return bnrelu4(ld4(src + (size_t)c * NPOS), ssc[S1_HD1 + c], ssh[S1_HD1 + c]); },
            wlds, y + (size_t)(S2_HD2 + off) * NPOS, p, sumA, sumqA, S2_HD2 + off, red);
    }
}

// ---------------------------------------------------------------------------
// Stage 3: fu(2), hu(3), pu(7) -> blockIdx.y in [0,12)
// ---------------------------------------------------------------------------
__global__ void __launch_bounds__(256) stage3_kernel(
    const float* __restrict__ xp, const float* __restrict__ xh,
    const float* __restrict__ xf, const float* __restrict__ p_fea,
    const float* __restrict__ h_fea, const float* __restrict__ f_fea,
    const float* __restrict__ w_fu, const float* __restrict__ w_hu,
    const float* __restrict__ w_pu, float* __restrict__ ws)
{
    __shared__ __align__(16) float wlds[MT * 316];
    __shared__ float red[4 * MT * 2];
    __shared__ float ssc[130], ssh[130];             // stage-2 stat range
    int g = blockIdx.x * 256 + threadIdx.x;
    int p = g * 4;
    int b = (p >= HW) ? 1 : 0;
    int s = p - b * HW;
    float* y     = ws;
    float* sumA  = ws + (size_t)NSLOT * NPOS;
    float* sumqA = sumA + NSTAT;
    const float* scaleA = sumqA + NSTAT;
    const float* shiftA = scaleA + NSTAT;

    for (int i = threadIdx.x; i < 130; i += 256) {
        ssc[i] = scaleA[L2OFF + i]; ssh[i] = shiftA[L2OFF + i];
    }
    int yb = blockIdx.y;

    if (yb < 2) {            // fu: [f_fea; xf_new] (266) -> 10+10
        int off = yb * MT;
        stage_w<266, 268>(w_fu + off * 266, wlds);
        const float* fb   = f_fea + (size_t)b * 256 * HW + s;
        const float* yhf2 = y + (size_t)S2_HF2 * NPOS + p;
        const float* xf1  = xf + ((size_t)b * 20 + 10) * HW + s;
        conv4<266, 268>([&](int c) {
            if (c < 256) return ld4(fb + c * HW);
            int cc = c - 256;
            float4 v = bnrelu4(ld4(yhf2 + (size_t)cc * NPOS),
                               ssc[S2_HF2 - L2OFF + cc], ssh[S2_HF2 - L2OFF + cc]);
            float4 r0 = ld4(xf1 + cc * HW);
            return make_float4(v.x + r0.x, v.y + r0.y, v.z + r0.z, v.w + r0.w); },
            wlds, y + (size_t)(S3_FU + off) * NPOS, p, sumA, sumqA, ST3_FU + off, red);
    } else if (yb < 5) {     // hu: [h_fea; xhu; xhl] (276) -> 3 x 10
        int off = (yb - 2) * MT;
        stage_w<276, 276>(w_hu + off * 276, wlds);
        const float* hb    = h_fea + (size_t)b * 256 * HW + s;
        const float* yphu2 = y + (size_t)S2_PHU2 * NPOS + p;
        const float* yphl2 = y + (size_t)S2_PHL2 * NPOS + p;
        const float* yfd2  = y + (size_t)S2_FD2 * NPOS + p;
        const float* xh1b  = xh + ((size_t)b * 30 + 10) * HW + s;
        conv4<276, 276>([&](int c) {
            if (c < 256) return ld4(hb + c * HW);
            if (c < 266) {
                int cc = c - 256;
                float4 a = bnrelu4(ld4(yphu2 + (size_t)cc * NPOS),
                                   ssc[S2_PHU2 - L2OFF + cc], ssh[S2_PHU2 - L2OFF + cc]);
                float4 f = bnrelu4(ld4(yfd2 + (size_t)(10 + cc) * NPOS),
                                   ssc[S2_FD2 - L2OFF + 10 + cc], ssh[S2_FD2 - L2OFF + 10 + cc]);
                float4 r0 = ld4(xh1b + cc * HW);
                return make_float4(r0.x + a.x + f.x, r0.y + a.y + f.y,
                                   r0.z + a.z + f.z, r0.w + a.w + f.w);
            }
            int cc = c - 266;
            float4 a = bnrelu4(ld4(yphl2 + (size_t)cc * NPOS),
                               ssc[S2_PHL2 - L2OFF + cc], ssh[S2_PHL2 - L2OFF + cc]);
            float4 f = bnrelu4(ld4(yfd2 + (size_t)(20 + cc) * NPOS),
                               ssc[S2_FD2 - L2OFF + 20 + cc], ssh[S2_FD2 - L2OFF + 20 + cc]);
            float4 r0 = ld4(xh1b + (10 + cc) * HW);
            return make_float4(r0.x + a.x + f.x, r0.y + a.y + f.y,
                               r0.z + a.z + f.z, r0.w + a.w + f.w); },
            wlds, y + (size_t)(S3_HU + off) * NPOS, p, sumA, sumqA, ST3_HU + off, red);
    } else {                 // pu: [p_fea; xp_new(60)] (316) -> 7 x 10
        int off = (yb - 5) * MT;
        stage_w<316, 316>(w_pu + off * 316, wlds);
        const float* pb   = p_fea + (size_t)b * 256 * HW + s;
        const float* yhd2 = y + (size_t)S2_HD2 * NPOS + p;
        const float* xpb  = xp + ((size_t)b * 70 + 10) * HW + s;
        conv4<316, 316>([&](int c) {
            if (c < 256) return ld4(pb + c * HW);
            int cc = c - 256;
            float4 v = bnrelu4(ld4(yhd2 + (size_t)(10 + cc) * NPOS),
                               ssc[S2_HD2 - L2OFF + 10 + cc], ssh[S2_HD2 - L2OFF + 10 + cc]);
            float4 r0 = ld4(xpb + cc * HW);
            return make_float4(v.x + r0.x, v.y + r0.y, v.z + r0.z, v.w + r0.w); },
            wlds, y + (size_t)(S3_PU + off) * NPOS, p, sumA, sumqA, ST3_PU + off, red);
    }
}

// ---------------------------------------------------------------------------
// Final: bn+relu all 220 output channels, float4
// out = concat([xp_upd(70), xh_upd(30), xf_upd(20), xfh(30), xhp(70)])
// ---------------------------------------------------------------------------
__global__ void __launch_bounds__(256) final_kernel(const float* __restrict__ ws,
                                                    float* __restrict__ out)
{
    int g = blockIdx.x * 256 + threadIdx.x;
    int p = g * 4;
    int c = blockIdx.y;
    const float* sumA   = ws + (size_t)NSLOT * NPOS;
    const float* scaleA = sumA + 2 * NSTAT;
    const float* shiftA = scaleA + NSTAT;
    int slot, stat;
    if      (c < 70)  { slot = S3_PU  + c;         stat = ST3_PU  + c;         }
    else if (c < 100) { slot = S3_HU  + (c - 70);  stat = ST3_HU  + (c - 70);  }
    else if (c < 120) { slot = S3_FU  + (c - 100); stat = ST3_FU  + (c - 100); }
    else if (c < 150) { slot = S2_FD2 + (c - 120); stat = S2_FD2 + (c - 120);  }
    else              { slot = S2_HD2 + (c - 150); stat = S2_HD2 + (c - 150);  }
    float4 v = *(const float4*)(ws + (size_t)slot * NPOS + p);
    float sc = scaleA[stat], sh = shiftA[stat];
    v.x = fmaf(v.x, sc, sh); v.x = v.x > 0.f ? v.x : 0.f;
    v.y = fmaf(v.y, sc, sh); v.y = v.y > 0.f ? v.y : 0.f;
    v.z = fmaf(v.z, sc, sh); v.z = v.z > 0.f ? v.z : 0.f;
    v.w = fmaf(v.w, sc, sh); v.w = v.w > 0.f ? v.w : 0.f;
    int b = (p >= HW) ? 1 : 0;
    int s = p - b * HW;
    *(float4*)(out + ((size_t)b * 220 + c) * HW + s) = v;
}

// ---------------------------------------------------------------------------
extern "C" void kernel_launch(void* const* d_in, const int* in_sizes, int n_in,
                              void* d_out, int out_size, void* d_ws, size_t ws_size,
                              hipStream_t stream)
{
    const float* xp     = (const float*)d_in[0];
    const float* xh     = (const float*)d_in[1];
    const float* xf     = (const float*)d_in[2];
    const float* p_fea  = (const float*)d_in[3];
    const float* h_fea  = (const float*)d_in[4];
    const float* f_fea  = (const float*)d_in[5];
    const float* w_hf1  = (const float*)d_in[6];  const float* bn_hf1  = (const float*)d_in[7];
    const float* w_hf2  = (const float*)d_in[8];  const float* bn_hf2  = (const float*)d_in[9];
    const float* w_phu1 = (const float*)d_in[10]; const float* bn_phu1 = (const float*)d_in[11];
    const float* w_phu2 = (const float*)d_in[12]; const float* bn_phu2 = (const float*)d_in[13];
    const float* w_phl1 = (const float*)d_in[14]; const float* bn_phl1 = (const float*)d_in[15];
    const float* w_phl2 = (const float*)d_in[16]; const float* bn_phl2 = (const float*)d_in[17];
    const float* w_fd1  = (const float*)d_in[18]; const float* bn_fd1  = (const float*)d_in[19];
    const float* w_fd2  = (const float*)d_in[20]; const float* bn_fd2  = (const float*)d_in[21];
    const float* w_hd1  = (const float*)d_in[22]; const float* bn_hd1  = (const float*)d_in[23];
    const float* w_hd2  = (const float*)d_in[24]; const float* bn_hd2  = (const float*)d_in[25];
    const float* w_fu   = (const float*)d_in[26]; const float* bn_fu   = (const float*)d_in[27];
    const float* w_hu   = (const float*)d_in[28]; const float* bn_hu   = (const float*)d_in[29];
    const float* w_pu   = (const float*)d_in[30]; const float* bn_pu   = (const float*)d_in[31];

    float* ws  = (float*)d_ws;
    float* out = (float*)d_out;

    size_t need_bytes = ((size_t)NSLOT * NPOS + 4 * NSTAT) * sizeof(float);
    if (ws_size < need_bytes) return;

    hipMemsetAsync(ws + (size_t)NSLOT * NPOS, 0, 2 * NSTAT * sizeof(float), stream);

    dim3 blk(256);
    const int GX = NPOS / 1024;   // 72 x-blocks, 4 positions/thread
    stage1_kernel<<<dim3(GX, 16), blk, 0, stream>>>(xp, xh, xf, p_fea, h_fea,
                                                    w_hf1, w_fd1, w_phu1, w_phl1, w_hd1, ws);
    scale_kernel<<<1, 256, 0, stream>>>(1, bn_hf1, bn_hf2, bn_phu1, bn_phu2, bn_phl1, bn_phl2,
                                        bn_fd1, bn_fd2, bn_hd1, bn_hd2, bn_fu, bn_hu, bn_pu, ws);
    stage2_kernel<<<dim3(GX, 13), blk, 0, stream>>>(w_hf2, w_fd2, w_phu2, w_phl2, w_hd2, ws);
    scale_kernel<<<1, 256, 0, stream>>>(2, bn_hf1, bn_hf2, bn_phu1, bn_phu2, bn_phl1, bn_phl2,
                                        bn_fd1, bn_fd2, bn_hd1, bn_hd2, bn_fu, bn_hu, bn_pu, ws);
    stage3_kernel<<<dim3(GX, 12), blk, 0, stream>>>(xp, xh, xf, p_fea, h_fea, f_fea,
                                                    w_fu, w_hu, w_pu, ws);
    scale_kernel<<<1, 256, 0, stream>>>(3, bn_hf1, bn_hf2, bn_phu1, bn_phu2, bn_phl1, bn_phl2,
                                        bn_fd1, bn_fd2, bn_hd1, bn_hd2, bn_fu, bn_hu, bn_pu, ws);
    final_kernel<<<dim3(NPOS / 1024, 220), blk, 0, stream>>>(ws, out);
}

// Round 3
// 604.407 us; speedup vs baseline: 1.2574x; 1.0361x over previous
//
#include <hip/hip_runtime.h>

#define HW   36864      // 192*192
#define NPOS 73728      // B*HW, B=2
#define EPSV 1e-5f

// channel-slot layout in workspace (each slot = NPOS floats)
#define S1_HF1  0
#define S1_FD1  20
#define S1_PHU1 50
#define S1_PHL1 70
#define S1_HD1  90
#define S2_HF2  160
#define S2_FD2  170
#define S2_PHU2 200
#define S2_PHL2 210
#define S2_HD2  220
#define S3_FU   0       // reuse stage-1 slots (dead by stage 3)
#define S3_HU   20
#define S3_PU   50
#define ST3_FU  290     // stat-channel bases for stage 3
#define ST3_HU  310
#define ST3_PU  340
#define NSLOT 290
#define NSTAT 410
#define L2OFF 160       // stage-2 stat range starts at 160

#define MT 10           // output channels per block (COUT slice)

__device__ __forceinline__ float4 ld4(const float* p) { return *(const float4*)p; }

__device__ __forceinline__ float4 bnrelu4(float4 v, float sc, float sh) {
    float4 r;
    r.x = fmaf(v.x, sc, sh); r.y = fmaf(v.y, sc, sh);
    r.z = fmaf(v.z, sc, sh); r.w = fmaf(v.w, sc, sh);
    r.x = r.x > 0.f ? r.x : 0.f;
    r.y = r.y > 0.f ? r.y : 0.f;
    r.z = r.z > 0.f ? r.z : 0.f;
    r.w = r.w > 0.f ? r.w : 0.f;
    return r;
}

// ---------------------------------------------------------------------------
// Stage this block's MT-row weight slice into LDS, rows padded to CINP floats
// (multiple of 4) so weight reads are broadcast ds_read_b128 (conflict-free).
// ---------------------------------------------------------------------------
template<int CIN, int CINP>
__device__ __forceinline__ void stage_w(const float* __restrict__ w, float* wl)
{
    if (CIN == CINP) {
        for (int idx = threadIdx.x; idx < MT * CIN; idx += 256)
            wl[idx] = w[idx];
    } else {
        for (int idx = threadIdx.x; idx < MT * CIN; idx += 256) {
            int o = idx / CIN;
            int c = idx - o * CIN;
            wl[o * CINP + c] = w[idx];
        }
    }
    __syncthreads();
}

// 4 channels x 4 positions for one output channel: 16 fmaf, channel-ascending
__device__ __forceinline__ void fma4x4(float4& a, float4 w, const float4* buf)
{
    a.x = fmaf(w.x, buf[0].x, a.x); a.y = fmaf(w.x, buf[0].y, a.y);
    a.z = fmaf(w.x, buf[0].z, a.z); a.w = fmaf(w.x, buf[0].w, a.w);
    a.x = fmaf(w.y, buf[1].x, a.x); a.y = fmaf(w.y, buf[1].y, a.y);
    a.z = fmaf(w.y, buf[1].z, a.z); a.w = fmaf(w.y, buf[1].w, a.w);
    a.x = fmaf(w.z, buf[2].x, a.x); a.y = fmaf(w.z, buf[2].y, a.y);
    a.z = fmaf(w.z, buf[2].z, a.z); a.w = fmaf(w.z, buf[2].w, a.w);
    a.x = fmaf(w.w, buf[3].x, a.x); a.y = fmaf(w.w, buf[3].y, a.y);
    a.z = fmaf(w.w, buf[3].z, a.z); a.w = fmaf(w.w, buf[3].w, a.w);
}

// ---------------------------------------------------------------------------
// Register-tiled conv slice: each thread owns FOUR positions (float4), block
// computes MT=10 output channels. CHUNK=8 software pipeline: the 8 global
// loads for chunk k+1 issue before the 320-fmaf block of chunk k (load->use
// distance ~640 cy/wave, ~1280 cy wall at 2 waves/SIMD -> covers ~900 cy
// cold-HBM latency). Weights broadcast from LDS.
// Per-position accumulation order is channel-ascending (matches reference).
// ---------------------------------------------------------------------------
template<int CIN, int CINP, class F>
__device__ __forceinline__ void conv4(F fetch, const float* wl,
                                      float* __restrict__ y, int p,
                                      float* __restrict__ sumA,
                                      float* __restrict__ sumqA,
                                      int stat0, float* red)
{
    float4 acc[MT];
#pragma unroll
    for (int o = 0; o < MT; ++o) acc[o] = make_float4(0.f, 0.f, 0.f, 0.f);

    constexpr int CHUNK = 8;
    constexpr int MAIN = (CIN / CHUNK) * CHUNK;
    if (MAIN > 0) {
        float4 buf[CHUNK];
#pragma unroll
        for (int i = 0; i < CHUNK; ++i) buf[i] = fetch(i);
#pragma unroll 1
        for (int c0 = CHUNK; c0 < MAIN; c0 += CHUNK) {
            float4 nxt[CHUNK];
#pragma unroll
            for (int i = 0; i < CHUNK; ++i) nxt[i] = fetch(c0 + i);   // prefetch
            const float* wb = wl + (c0 - CHUNK);
#pragma unroll
            for (int o = 0; o < MT; ++o) {
                float4 w0 = ld4(wb + o * CINP);
                float4 w1 = ld4(wb + o * CINP + 4);
                fma4x4(acc[o], w0, buf);
                fma4x4(acc[o], w1, buf + 4);
            }
#pragma unroll
            for (int i = 0; i < CHUNK; ++i) buf[i] = nxt[i];
        }
        const float* wb = wl + (MAIN - CHUNK);
#pragma unroll
        for (int o = 0; o < MT; ++o) {                // drain last chunk
            float4 w0 = ld4(wb + o * CINP);
            float4 w1 = ld4(wb + o * CINP + 4);
            fma4x4(acc[o], w0, buf);
            fma4x4(acc[o], w1, buf + 4);
        }
    }
    constexpr int REM = CIN - MAIN;
    int ct = MAIN;
    if (REM >= 4) {                                   // vector tail (4 channels)
        float4 buf4[4];
#pragma unroll
        for (int i = 0; i < 4; ++i) buf4[i] = fetch(ct + i);
#pragma unroll
        for (int o = 0; o < MT; ++o)
            fma4x4(acc[o], ld4(wl + ct + o * CINP), buf4);
        ct += 4;
    }
#pragma unroll
    for (int c = ct; c < CIN; ++c) {                  // scalar tail
        float4 x = fetch(c);
#pragma unroll
        for (int o = 0; o < MT; ++o) {
            float wv = wl[o * CINP + c];
            acc[o].x = fmaf(wv, x.x, acc[o].x);
            acc[o].y = fmaf(wv, x.y, acc[o].y);
            acc[o].z = fmaf(wv, x.z, acc[o].z);
            acc[o].w = fmaf(wv, x.w, acc[o].w);
        }
    }

#pragma unroll
    for (int o = 0; o < MT; ++o)
        *(float4*)(y + (size_t)o * NPOS + p) = acc[o];

    int lane = threadIdx.x & 63;
    int wv_  = threadIdx.x >> 6;
#pragma unroll
    for (int o = 0; o < MT; ++o) {
        float s = (acc[o].x + acc[o].y) + (acc[o].z + acc[o].w);
        float q = (acc[o].x * acc[o].x + acc[o].y * acc[o].y)
                + (acc[o].z * acc[o].z + acc[o].w * acc[o].w);
#pragma unroll
        for (int i = 1; i < 64; i <<= 1) {
            s += __shfl_xor(s, i, 64);
            q += __shfl_xor(q, i, 64);
        }
        if (lane == 0) {
            red[(wv_ * MT + o) * 2]     = s;
            red[(wv_ * MT + o) * 2 + 1] = q;
        }
    }
    __syncthreads();
    if (threadIdx.x < MT) {
        int o = threadIdx.x;
        float s = 0.f, q = 0.f;
#pragma unroll
        for (int k = 0; k < 4; ++k) {
            s += red[(k * MT + o) * 2];
            q += red[(k * MT + o) * 2 + 1];
        }
        atomicAdd(&sumA[stat0 + o], s);
        atomicAdd(&sumqA[stat0 + o], q);
    }
}

// ---------------------------------------------------------------------------
// Stage 1 (heavy-first y-order): hd1(0..6), fd1(7..9), hf1(10,11),
//                                phu1(12,13), phl1(14,15)
// ---------------------------------------------------------------------------
__global__ void __launch_bounds__(256) stage1_kernel(
    const float* __restrict__ xp, const float* __restrict__ xh,
    const float* __restrict__ xf, const float* __restrict__ p_fea,
    const float* __restrict__ h_fea,
    const float* __restrict__ w_hf1, const float* __restrict__ w_fd1,
    const float* __restrict__ w_phu1, const float* __restrict__ w_phl1,
    const float* __restrict__ w_hd1, float* __restrict__ ws)
{
    __shared__ __align__(16) float wlds[MT * 276];
    __shared__ float red[4 * MT * 2];
    int g = blockIdx.x * 256 + threadIdx.x;
    int p = g * 4;
    int b = (p >= HW) ? 1 : 0;
    int s = p - b * HW;
    float* y     = ws;
    float* sumA  = ws + (size_t)NSLOT * NPOS;
    float* sumqA = sumA + NSTAT;
    int yb = blockIdx.y;

    if (yb < 7) {            // hd1: [p_fea; xh1; xh2] (276) -> 7 x 10
        int off = yb * MT;
        stage_w<276, 276>(w_hd1 + off * 276, wlds);
        const float* pb = p_fea + (size_t)b * 256 * HW + s;
        const float* xb = xh + ((size_t)b * 30 + 10) * HW + s;
        conv4<276, 276>([&](int c) { return (c < 256) ? ld4(pb + c * HW)
                                                      : ld4(xb + (c - 256) * HW); },
                        wlds, y + (size_t)(S1_HD1 + off) * NPOS, p,
                        sumA, sumqA, S1_HD1 + off, red);
    } else if (yb < 10) {    // fd1: [h_fea; xf1] (266) -> 3 x 10
        int off = (yb - 7) * MT;
        stage_w<266, 268>(w_fd1 + off * 266, wlds);
        const float* hb  = h_fea + (size_t)b * 256 * HW + s;
        const float* xf1 = xf + ((size_t)b * 20 + 10) * HW + s;
        conv4<266, 268>([&](int c) { return (c < 256) ? ld4(hb + c * HW)
                                                      : ld4(xf1 + (c - 256) * HW); },
                        wlds, y + (size_t)(S1_FD1 + off) * NPOS, p,
                        sumA, sumqA, S1_FD1 + off, red);
    } else if (yb < 12) {    // hf1: [xh1; xh2] (20) -> 10+10
        int off = (yb - 10) * MT;
        stage_w<20, 20>(w_hf1 + off * 20, wlds);
        const float* xb = xh + ((size_t)b * 30 + 10) * HW + s;
        conv4<20, 20>([&](int c) { return ld4(xb + c * HW); },
                      wlds, y + (size_t)(S1_HF1 + off) * NPOS, p,
                      sumA, sumqA, S1_HF1 + off, red);
    } else if (yb < 14) {    // phu1: xp[1:5] (40) -> 10+10
        int off = (yb - 12) * MT;
        stage_w<40, 40>(w_phu1 + off * 40, wlds);
        const float* xb = xp + ((size_t)b * 70 + 10) * HW + s;
        conv4<40, 40>([&](int c) { return ld4(xb + c * HW); },
                      wlds, y + (size_t)(S1_PHU1 + off) * NPOS, p,
                      sumA, sumqA, S1_PHU1 + off, red);
    } else {                 // phl1: xp[5:7] (20) -> 10+10
        int off = (yb - 14) * MT;
        stage_w<20, 20>(w_phl1 + off * 20, wlds);
        const float* xb = xp + ((size_t)b * 70 + 50) * HW + s;
        conv4<20, 20>([&](int c) { return ld4(xb + c * HW); },
                      wlds, y + (size_t)(S1_PHL1 + off) * NPOS, p,
                      sumA, sumqA, S1_PHL1 + off, red);
    }
}

// ---------------------------------------------------------------------------
// scale/shift from accumulated stats
// ---------------------------------------------------------------------------
__global__ void scale_kernel(int stage,
    const float* __restrict__ bn_hf1, const float* __restrict__ bn_hf2,
    const float* __restrict__ bn_phu1, const float* __restrict__ bn_phu2,
    const float* __restrict__ bn_phl1, const float* __restrict__ bn_phl2,
    const float* __restrict__ bn_fd1, const float* __restrict__ bn_fd2,
    const float* __restrict__ bn_hd1, const float* __restrict__ bn_hd2,
    const float* __restrict__ bn_fu, const float* __restrict__ bn_hu,
    const float* __restrict__ bn_pu, float* __restrict__ ws)
{
    int t = threadIdx.x;
    float* sumA   = ws + (size_t)NSLOT * NPOS;
    float* sumqA  = sumA + NSTAT;
    float* scaleA = sumqA + NSTAT;
    float* shiftA = scaleA + NSTAT;
    int stat, local, co;
    const float* bn;
    if (stage == 1) {
        if (t >= 160) return;
        stat = t;
        if      (t < 20) { bn = bn_hf1;  local = t;      co = 20; }
        else if (t < 50) { bn = bn_fd1;  local = t - 20; co = 30; }
        else if (t < 70) { bn = bn_phu1; local = t - 50; co = 20; }
        else if (t < 90) { bn = bn_phl1; local = t - 70; co = 20; }
        else             { bn = bn_hd1;  local = t - 90; co = 70; }
    } else if (stage == 2) {
        if (t >= 130) return;
        stat = 160 + t;
        if      (t < 10) { bn = bn_hf2;  local = t;      co = 10; }
        else if (t < 40) { bn = bn_fd2;  local = t - 10; co = 30; }
        else if (t < 50) { bn = bn_phu2; local = t - 40; co = 10; }
        else if (t < 60) { bn = bn_phl2; local = t - 50; co = 10; }
        else             { bn = bn_hd2;  local = t - 60; co = 70; }
    } else {
        if (t >= 120) return;
        stat = 290 + t;
        if      (t < 20) { bn = bn_fu; local = t;      co = 20; }
        else if (t < 50) { bn = bn_hu; local = t - 20; co = 30; }
        else             { bn = bn_pu; local = t - 50; co = 70; }
    }
    float n  = (float)NPOS;
    float m  = sumA[stat] / n;
    float v  = sumqA[stat] / n - m * m;
    float g  = bn[local];
    float bt = bn[co + local];
    float sc = g * rsqrtf(v + EPSV);
    scaleA[stat] = sc;
    shiftA[stat] = bt - m * sc;
}

// ---------------------------------------------------------------------------
// Stage 2 (heavy-first): hd2(0..6), fd2(7..9), hf2(10), phu2(11), phl2(12)
// ---------------------------------------------------------------------------
__global__ void __launch_bounds__(256) stage2_kernel(
    const float* __restrict__ w_hf2, const float* __restrict__ w_fd2,
    const float* __restrict__ w_phu2, const float* __restrict__ w_phl2,
    const float* __restrict__ w_hd2, float* __restrict__ ws)
{
    __shared__ __align__(16) float wlds[MT * 72];
    __shared__ float red[4 * MT * 2];
    __shared__ float ssc[160], ssh[160];
    int g = blockIdx.x * 256 + threadIdx.x;
    int p = g * 4;
    float* y     = ws;
    float* sumA  = ws + (size_t)NSLOT * NPOS;
    float* sumqA = sumA + NSTAT;
    const float* scaleA = sumqA + NSTAT;
    const float* shiftA = scaleA + NSTAT;

    for (int i = threadIdx.x; i < 160; i += 256) { ssc[i] = scaleA[i]; ssh[i] = shiftA[i]; }
    int yb = blockIdx.y;

    if (yb < 7) {            // hd2: hd1(70) -> 7 x 10
        int off = yb * MT;
        stage_w<70, 72>(w_hd2 + off * 70, wlds);
        const float* src = y + (size_t)S1_HD1 * NPOS + p;
        conv4<70, 72>([&](int c) {
            return bnrelu4(ld4(src + (size_t)c * NPOS), ssc[S1_HD1 + c], ssh[S1_HD1 + c]); },
            wlds, y + (size_t)(S2_HD2 + off) * NPOS, p, sumA, sumqA, S2_HD2 + off, red);
    } else if (yb < 10) {    // fd2: fd1(30) -> 3 x 10
        int off = (yb - 7) * MT;
        stage_w<30, 32>(w_fd2 + off * 30, wlds);
        const float* src = y + (size_t)S1_FD1 * NPOS + p;
        conv4<30, 32>([&](int c) {
            return bnrelu4(ld4(src + (size_t)c * NPOS), ssc[S1_FD1 + c], ssh[S1_FD1 + c]); },
            wlds, y + (size_t)(S2_FD2 + off) * NPOS, p, sumA, sumqA, S2_FD2 + off, red);
    } else if (yb == 10) {   // hf2: hf1(20) -> 10
        stage_w<20, 20>(w_hf2, wlds);
        const float* src = y + (size_t)S1_HF1 * NPOS + p;
        conv4<20, 20>([&](int c) {
            return bnrelu4(ld4(src + (size_t)c * NPOS), ssc[S1_HF1 + c], ssh[S1_HF1 + c]); },
            wlds, y + (size_t)S2_HF2 * NPOS, p, sumA, sumqA, S2_HF2, red);
    } else if (yb == 11) {   // phu2: phu1(20) -> 10
        stage_w<20, 20>(w_phu2, wlds);
        const float* src = y + (size_t)S1_PHU1 * NPOS + p;
        conv4<20, 20>([&](int c) {
            return bnrelu4(ld4(src + (size_t)c * NPOS), ssc[S1_PHU1 + c], ssh[S1_PHU1 + c]); },
            wlds, y + (size_t)S2_PHU2 * NPOS, p, sumA, sumqA, S2_PHU2, red);
    } else {                 // phl2: phl1(20) -> 10
        stage_w<20, 20>(w_phl2, wlds);
        const float* src = y + (size_t)S1_PHL1 * NPOS + p;
        conv4<20, 20>([&](int c) {
            return bnrelu4(ld4(src + (size_t)c * NPOS), ssc[S1_PHL1 + c], ssh[S1_PHL1 + c]); },
            wlds, y + (size_t)S2_PHL2 * NPOS, p, sumA, sumqA, S2_PHL2, red);
    }
}

// ---------------------------------------------------------------------------
// Stage 3 (heavy-first): pu(0..6), hu(7..9), fu(10,11)
// ---------------------------------------------------------------------------
__global__ void __launch_bounds__(256) stage3_kernel(
    const float* __restrict__ xp, const float* __restrict__ xh,
    const float* __restrict__ xf, const float* __restrict__ p_fea,
    const float* __restrict__ h_fea, const float* __restrict__ f_fea,
    const float* __restrict__ w_fu, const float* __restrict__ w_hu,
    const float* __restrict__ w_pu, float* __restrict__ ws)
{
    __shared__ __align__(16) float wlds[MT * 316];
    __shared__ float red[4 * MT * 2];
    __shared__ float ssc[130], ssh[130];             // stage-2 stat range
    int g = blockIdx.x * 256 + threadIdx.x;
    int p = g * 4;
    int b = (p >= HW) ? 1 : 0;
    int s = p - b * HW;
    float* y     = ws;
    float* sumA  = ws + (size_t)NSLOT * NPOS;
    float* sumqA = sumA + NSTAT;
    const float* scaleA = sumqA + NSTAT;
    const float* shiftA = scaleA + NSTAT;

    for (int i = threadIdx.x; i < 130; i += 256) {
        ssc[i] = scaleA[L2OFF + i]; ssh[i] = shiftA[L2OFF + i];
    }
    int yb = blockIdx.y;

    if (yb < 7) {            // pu: [p_fea; xp_new(60)] (316) -> 7 x 10
        int off = yb * MT;
        stage_w<316, 316>(w_pu + off * 316, wlds);
        const float* pb   = p_fea + (size_t)b * 256 * HW + s;
        const float* yhd2 = y + (size_t)S2_HD2 * NPOS + p;
        const float* xpb  = xp + ((size_t)b * 70 + 10) * HW + s;
        conv4<316, 316>([&](int c) {
            if (c < 256) return ld4(pb + c * HW);
            int cc = c - 256;
            float4 v = bnrelu4(ld4(yhd2 + (size_t)(10 + cc) * NPOS),
                               ssc[S2_HD2 - L2OFF + 10 + cc], ssh[S2_HD2 - L2OFF + 10 + cc]);
            float4 r0 = ld4(xpb + cc * HW);
            return make_float4(v.x + r0.x, v.y + r0.y, v.z + r0.z, v.w + r0.w); },
            wlds, y + (size_t)(S3_PU + off) * NPOS, p, sumA, sumqA, ST3_PU + off, red);
    } else if (yb < 10) {    // hu: [h_fea; xhu; xhl] (276) -> 3 x 10
        int off = (yb - 7) * MT;
        stage_w<276, 276>(w_hu + off * 276, wlds);
        const float* hb    = h_fea + (size_t)b * 256 * HW + s;
        const float* yphu2 = y + (size_t)S2_PHU2 * NPOS + p;
        const float* yphl2 = y + (size_t)S2_PHL2 * NPOS + p;
        const float* yfd2  = y + (size_t)S2_FD2 * NPOS + p;
        const float* xh1b  = xh + ((size_t)b * 30 + 10) * HW + s;
        conv4<276, 276>([&](int c) {
            if (c < 256) return ld4(hb + c * HW);
            if (c < 266) {
                int cc = c - 256;
                float4 a = bnrelu4(ld4(yphu2 + (size_t)cc * NPOS),
                                   ssc[S2_PHU2 - L2OFF + cc], ssh[S2_PHU2 - L2OFF + cc]);
                float4 f = bnrelu4(ld4(yfd2 + (size_t)(10 + cc) * NPOS),
                                   ssc[S2_FD2 - L2OFF + 10 + cc], ssh[S2_FD2 - L2OFF + 10 + cc]);
                float4 r0 = ld4(xh1b + cc * HW);
                return make_float4(r0.x + a.x + f.x, r0.y + a.y + f.y,
                                   r0.z + a.z + f.z, r0.w + a.w + f.w);
            }
            int cc = c - 266;
            float4 a = bnrelu4(ld4(yphl2 + (size_t)cc * NPOS),
                               ssc[S2_PHL2 - L2OFF + cc], ssh[S2_PHL2 - L2OFF + cc]);
            float4 f = bnrelu4(ld4(yfd2 + (size_t)(20 + cc) * NPOS),
                               ssc[S2_FD2 - L2OFF + 20 + cc], ssh[S2_FD2 - L2OFF + 20 + cc]);
            float4 r0 = ld4(xh1b + (10 + cc) * HW);
            return make_float4(r0.x + a.x + f.x, r0.y + a.y + f.y,
                               r0.z + a.z + f.z, r0.w + a.w + f.w); },
            wlds, y + (size_t)(S3_HU + off) * NPOS, p, sumA, sumqA, ST3_HU + off, red);
    } else {                 // fu: [f_fea; xf_new] (266) -> 10+10
        int off = (yb - 10) * MT;
        stage_w<266, 268>(w_fu + off * 266, wlds);
        const float* fb   = f_fea + (size_t)b * 256 * HW + s;
        const float* yhf2 = y + (size_t)S2_HF2 * NPOS + p;
        const float* xf1  = xf + ((size_t)b * 20 + 10) * HW + s;
        conv4<266, 268>([&](int c) {
            if (c < 256) return ld4(fb + c * HW);
            int cc = c - 256;
            float4 v = bnrelu4(ld4(yhf2 + (size_t)cc * NPOS),
                               ssc[S2_HF2 - L2OFF + cc], ssh[S2_HF2 - L2OFF + cc]);
            float4 r0 = ld4(xf1 + cc * HW);
            return make_float4(v.x + r0.x, v.y + r0.y, v.z + r0.z, v.w + r0.w); },
            wlds, y + (size_t)(S3_FU + off) * NPOS, p, sumA, sumqA, ST3_FU + off, red);
    }
}

// ---------------------------------------------------------------------------
// Final: bn+relu all 220 output channels, float4
// out = concat([xp_upd(70), xh_upd(30), xf_upd(20), xfh(30), xhp(70)])
// ---------------------------------------------------------------------------
__global__ void __launch_bounds__(256) final_kernel(const float* __restrict__ ws,
                                                    float* __restrict__ out)
{
    int g = blockIdx.x * 256 + threadIdx.x;
    int p = g * 4;
    int c = blockIdx.y;
    const float* sumA   = ws + (size_t)NSLOT * NPOS;
    const float* scaleA = sumA + 2 * NSTAT;
    const float* shiftA = scaleA + NSTAT;
    int slot, stat;
    if      (c < 70)  { slot = S3_PU  + c;         stat = ST3_PU  + c;         }
    else if (c < 100) { slot = S3_HU  + (c - 70);  stat = ST3_HU  + (c - 70);  }
    else if (c < 120) { slot = S3_FU  + (c - 100); stat = ST3_FU  + (c - 100); }
    else if (c < 150) { slot = S2_FD2 + (c - 120); stat = S2_FD2 + (c - 120);  }
    else              { slot = S2_HD2 + (c - 150); stat = S2_HD2 + (c - 150);  }
    float4 v = *(const float4*)(ws + (size_t)slot * NPOS + p);
    float sc = scaleA[stat], sh = shiftA[stat];
    v.x = fmaf(v.x, sc, sh); v.x = v.x > 0.f ? v.x : 0.f;
    v.y = fmaf(v.y, sc, sh); v.y = v.y > 0.f ? v.y : 0.f;
    v.z = fmaf(v.z, sc, sh); v.z = v.z > 0.f ? v.z : 0.f;
    v.w = fmaf(v.w, sc, sh); v.w = v.w > 0.f ? v.w : 0.f;
    int b = (p >= HW) ? 1 : 0;
    int s = p - b * HW;
    *(float4*)(out + ((size_t)b * 220 + c) * HW + s) = v;
}

// ---------------------------------------------------------------------------
extern "C" void kernel_launch(void* const* d_in, const int* in_sizes, int n_in,
                              void* d_out, int out_size, void* d_ws, size_t ws_size,
                              hipStream_t stream)
{
    const float* xp     = (const float*)d_in[0];
    const float* xh     = (const float*)d_in[1];
    const float* xf     = (const float*)d_in[2];
    const float* p_fea  = (const float*)d_in[3];
    const float* h_fea  = (const float*)d_in[4];
    const float* f_fea  = (const float*)d_in[5];
    const float* w_hf1  = (const float*)d_in[6];  const float* bn_hf1  = (const float*)d_in[7];
    const float* w_hf2  = (const float*)d_in[8];  const float* bn_hf2  = (const float*)d_in[9];
    const float* w_phu1 = (const float*)d_in[10]; const float* bn_phu1 = (const float*)d_in[11];
    const float* w_phu2 = (const float*)d_in[12]; const float* bn_phu2 = (const float*)d_in[13];
    const float* w_phl1 = (const float*)d_in[14]; const float* bn_phl1 = (const float*)d_in[15];
    const float* w_phl2 = (const float*)d_in[16]; const float* bn_phl2 = (const float*)d_in[17];
    const float* w_fd1  = (const float*)d_in[18]; const float* bn_fd1  = (const float*)d_in[19];
    const float* w_fd2  = (const float*)d_in[20]; const float* bn_fd2  = (const float*)d_in[21];
    const float* w_hd1  = (const float*)d_in[22]; const float* bn_hd1  = (const float*)d_in[23];
    const float* w_hd2  = (const float*)d_in[24]; const float* bn_hd2  = (const float*)d_in[25];
    const float* w_fu   = (const float*)d_in[26]; const float* bn_fu   = (const float*)d_in[27];
    const float* w_hu   = (const float*)d_in[28]; const float* bn_hu   = (const float*)d_in[29];
    const float* w_pu   = (const float*)d_in[30]; const float* bn_pu   = (const float*)d_in[31];

    float* ws  = (float*)d_ws;
    float* out = (float*)d_out;

    size_t need_bytes = ((size_t)NSLOT * NPOS + 4 * NSTAT) * sizeof(float);
    if (ws_size < need_bytes) return;

    hipMemsetAsync(ws + (size_t)NSLOT * NPOS, 0, 2 * NSTAT * sizeof(float), stream);

    dim3 blk(256);
    const int GX = NPOS / 1024;   // 72 x-blocks, 4 positions/thread
    stage1_kernel<<<dim3(GX, 16), blk, 0, stream>>>(xp, xh, xf, p_fea, h_fea,
                                                    w_hf1, w_fd1, w_phu1, w_phl1, w_hd1, ws);
    scale_kernel<<<1, 256, 0, stream>>>(1, bn_hf1, bn_hf2, bn_phu1, bn_phu2, bn_phl1, bn_phl2,
                                        bn_fd1, bn_fd2, bn_hd1, bn_hd2, bn_fu, bn_hu, bn_pu, ws);
    stage2_kernel<<<dim3(GX, 13), blk, 0, stream>>>(w_hf2, w_fd2, w_phu2, w_phl2, w_hd2, ws);
    scale_kernel<<<1, 256, 0, stream>>>(2, bn_hf1, bn_hf2, bn_phu1, bn_phu2, bn_phl1, bn_phl2,
                                        bn_fd1, bn_fd2, bn_hd1, bn_hd2, bn_fu, bn_hu, bn_pu, ws);
    stage3_kernel<<<dim3(GX, 12), blk, 0, stream>>>(xp, xh, xf, p_fea, h_fea, f_fea,
                                                    w_fu, w_hu, w_pu, ws);
    scale_kernel<<<1, 256, 0, stream>>>(3, bn_hf1, bn_hf2, bn_phu1, bn_phu2, bn_phl1, bn_phl2,
                                        bn_fd1, bn_fd2, bn_hd1, bn_hd2, bn_fu, bn_hu, bn_pu, ws);
    final_kernel<<<dim3(NPOS / 1024, 220), blk, 0, stream>>>(ws, out);
}